// Round 8
// baseline (355.448 us; speedup 1.0000x reference)
//
#include <hip/hip_runtime.h>
#include <math.h>

#define D_IN 256
#define HID 128
#define D_OUT 64
#define NEG_SLOPE 0.2f

typedef short short8 __attribute__((ext_vector_type(8)));
typedef float floatx4 __attribute__((ext_vector_type(4)));

__device__ __forceinline__ float wave_reduce_sum(float v) {
    #pragma unroll
    for (int off = 32; off > 0; off >>= 1) v += __shfl_xor(v, off, 64);
    return v;
}
__device__ __forceinline__ int wave_reduce_sum_i(int v) {
    #pragma unroll
    for (int off = 32; off > 0; off >>= 1) v += __shfl_xor(v, off, 64);
    return v;
}
__device__ __forceinline__ int wave_scan_incl_i(int v) {
    int lane = threadIdx.x & 63;
    #pragma unroll
    for (int off = 1; off < 64; off <<= 1) {
        int t = __shfl_up(v, off, 64);
        if (lane >= off) v += t;
    }
    return v;
}

__device__ __forceinline__ short f2bf(float f) {           // RNE f32->bf16
    unsigned u = __float_as_uint(f);
    u += 0x7fffu + ((u >> 16) & 1u);
    return (short)(u >> 16);
}
__device__ __forceinline__ float bflo(unsigned p) { return __uint_as_float(p << 16); }
__device__ __forceinline__ float bfhi(unsigned p) { return __uint_as_float(p & 0xffff0000u); }

// ---- prep: GEMV att weights, folded biases ----
__global__ void prep_kernel(const float* __restrict__ Wsrc1, const float* __restrict__ att_src1,
                            const float* __restrict__ Wdst1, const float* __restrict__ att_dst1,
                            const float* __restrict__ Wsrc2, const float* __restrict__ att_src2,
                            const float* __restrict__ Wdst2, const float* __restrict__ att_dst2,
                            const float* __restrict__ b1, const float* __restrict__ b_lin1,
                            const float* __restrict__ b2, const float* __restrict__ b_lin2,
                            float* v_src1, float* v_dst1, float* v_src2, float* v_dst2,
                            float* bsum1, float* bsum2) {
    int t = threadIdx.x;
    if (t < D_IN) {
        float s1 = 0.f, s2 = 0.f;
        for (int c = 0; c < HID; c++) {
            s1 += Wsrc1[t * HID + c] * att_src1[c];
            s2 += Wdst1[t * HID + c] * att_dst1[c];
        }
        v_src1[t] = s1; v_dst1[t] = s2;
    }
    if (t < HID) {
        float s1 = 0.f, s2 = 0.f;
        for (int c = 0; c < D_OUT; c++) {
            s1 += Wsrc2[t * D_OUT + c] * att_src2[c];
            s2 += Wdst2[t * D_OUT + c] * att_dst2[c];
        }
        v_src2[t] = s1; v_dst2[t] = s2;
        bsum1[t] = b1[t] + b_lin1[t];
    }
    if (t < D_OUT) bsum2[t] = b2[t] + b_lin2[t];
}

// ---- pack [Wa | Wb] into bf16 B-fragment stream ----
// Wp[((s*NTG + nt)*64 + lane)*8 + j] = W[k][col], k = s*32 + (lane>>4)*8 + j,
// cg = nt*16 + (lane&15); cg < NH -> Wa col cg, else Wb col cg-NH.
__global__ void pack_kernel(const float* __restrict__ Wa, const float* __restrict__ Wb,
                            short* __restrict__ Wp, int NTG, int NH, int total) {
    int idx = blockIdx.x * 256 + threadIdx.x;
    if (idx >= total) return;
    int j = idx & 7;
    int lane = (idx >> 3) & 63;
    int r = idx >> 9;
    int nt = r % NTG;
    int s = r / NTG;
    int k = s * 32 + ((lane >> 4) * 8) + j;
    int cg = nt * 16 + (lane & 15);
    const float* W = (cg < NH) ? Wa : Wb;
    int col = (cg < NH) ? cg : cg - NH;
    Wp[idx] = f2bf(W[(size_t)k * NH + col]);
}

// ---- convert x fp32 -> bf16 + fused layer-1 attention dots (one wave per row) ----
__global__ void convert_kernel(const float* __restrict__ X,
                               const float* __restrict__ vsrc, const float* __restrict__ vdst,
                               unsigned short* __restrict__ xb,
                               float* __restrict__ a_src, float* __restrict__ a_dst, int Nn) {
    int row = blockIdx.x * 4 + (threadIdx.x >> 6);
    int lane = threadIdx.x & 63;
    if (row >= Nn) return;
    float4 v = *(const float4*)(X + (size_t)row * D_IN + lane * 4);
    float4 vs = *(const float4*)(vsrc + lane * 4);
    float4 vd = *(const float4*)(vdst + lane * 4);
    float ps = v.x * vs.x + v.y * vs.y + v.z * vs.z + v.w * vs.w;
    float pd = v.x * vd.x + v.y * vd.y + v.z * vd.z + v.w * vd.w;
    ushort4 o;
    o.x = (unsigned short)f2bf(v.x); o.y = (unsigned short)f2bf(v.y);
    o.z = (unsigned short)f2bf(v.z); o.w = (unsigned short)f2bf(v.w);
    *(ushort4*)(xb + (size_t)row * D_IN + lane * 4) = o;
    ps = wave_reduce_sum(ps);
    pd = wave_reduce_sum(pd);
    if (lane == 0) { a_src[row] = ps; a_dst[row] = pd; }
}

// ---- CSR build ----
__global__ void hist_kernel(const int* __restrict__ dst, int E, int* deg) {
    int e = blockIdx.x * 256 + threadIdx.x;
    if (e < E) atomicAdd(&deg[dst[e]], 1);
}

__global__ void scan_partial(const int* __restrict__ deg, int n, int* bsums) {
    __shared__ int ws[16];
    int i = blockIdx.x * 1024 + threadIdx.x;
    int v = (i < n) ? deg[i] : 0;
    int s = wave_reduce_sum_i(v);
    if ((threadIdx.x & 63) == 0) ws[threadIdx.x >> 6] = s;
    __syncthreads();
    if (threadIdx.x == 0) {
        int tot = 0;
        #pragma unroll
        for (int w = 0; w < 16; w++) tot += ws[w];
        bsums[blockIdx.x] = tot;
    }
}

__global__ void scan_offsets(const int* __restrict__ bsums, int nb, int* boff) {
    int lane = threadIdx.x;
    int v = (lane < nb) ? bsums[lane] : 0;
    int incl = wave_scan_incl_i(v);
    if (lane < nb) boff[lane] = incl - v;
}

__global__ void scan_final(const int* __restrict__ deg, int n, const int* __restrict__ boff,
                           int* row_ptr, int* cursor) {
    __shared__ int ws[16];
    int i = blockIdx.x * 1024 + threadIdx.x;
    int wid = threadIdx.x >> 6;
    int v = (i < n) ? deg[i] : 0;
    int sv = wave_scan_incl_i(v);
    if ((threadIdx.x & 63) == 63) ws[wid] = sv;
    __syncthreads();
    if (threadIdx.x == 0) {
        int run = 0;
        #pragma unroll
        for (int w = 0; w < 16; w++) { int t = ws[w]; ws[w] = run; run += t; }
    }
    __syncthreads();
    int excl = boff[blockIdx.x] + ws[wid] + sv - v;
    if (i < n) {
        row_ptr[i] = excl; cursor[i] = excl;
        if (i == n - 1) row_ptr[n] = excl + v;
    }
}

__global__ void scatter_kernel(const int* __restrict__ src, const int* __restrict__ dst, int E,
                               int* cursor, int* ssrc) {
    int e = blockIdx.x * 256 + threadIdx.x;
    if (e < E) {
        int d = dst[e];
        int pos = atomicAdd(&cursor[d], 1);
        ssrc[pos] = src[e];
    }
}

// ---- barrier-free direct-fragment MFMA GEMM ----
// A bf16 [M,K] row-major; Wp pre-packed fragment stream (NTG = 4*NT n-tiles/k-step).
// Block = 4 waves side-by-side in N; wave tile 64 x (NT*16). No LDS, no barriers:
// fragments load straight from L1/L2; full K unroll lets the compiler hoist loads.
// NH = 2*NT*16 cols per half; cg < NH -> outb bf16, else outc bf16 + bias.
template <int KS, int NT>
__global__ __launch_bounds__(256, 3) void gemm_direct(const unsigned short* __restrict__ A,
                                                      const short* __restrict__ Wp,
                                                      const float* __restrict__ bias,
                                                      unsigned short* __restrict__ outb,
                                                      unsigned short* __restrict__ outc, int M) {
    const int K = KS * 32;
    const int NTG = 4 * NT;
    const int NH = NT * 32;
    int tid = threadIdx.x;
    int wave = tid >> 6, lane = tid & 63;
    int mr = lane & 15, quad = lane >> 4;
    int bm = blockIdx.x * 64;

    floatx4 acc[4][NT];
    #pragma unroll
    for (int i = 0; i < 4; i++)
        #pragma unroll
        for (int j = 0; j < NT; j++) acc[i][j] = (floatx4){0.f, 0.f, 0.f, 0.f};

    const unsigned short* arow[4];
    #pragma unroll
    for (int tm = 0; tm < 4; tm++) {
        int gr = bm + tm * 16 + mr;
        if (gr >= M) gr = M - 1;
        arow[tm] = A + (size_t)gr * K + quad * 8;
    }
    const short* bbase = Wp + ((size_t)(wave * NT) * 64 + lane) * 8;

    #pragma unroll
    for (int s = 0; s < KS; s++) {
        short8 af[4], bf[NT];
        #pragma unroll
        for (int tm = 0; tm < 4; tm++)
            af[tm] = *(const short8*)(arow[tm] + s * 32);
        #pragma unroll
        for (int tn = 0; tn < NT; tn++)
            bf[tn] = *(const short8*)(bbase + ((size_t)s * NTG + tn) * 512);
        #pragma unroll
        for (int tn = 0; tn < NT; tn++)
            #pragma unroll
            for (int tm = 0; tm < 4; tm++)
                acc[tm][tn] = __builtin_amdgcn_mfma_f32_16x16x32_bf16(af[tm], bf[tn],
                                                                      acc[tm][tn], 0, 0, 0);
    }

    #pragma unroll
    for (int tm = 0; tm < 4; tm++) {
        #pragma unroll
        for (int tn = 0; tn < NT; tn++) {
            int cg = wave * NT * 16 + tn * 16 + mr;
            if (cg < NH) {
                #pragma unroll
                for (int r = 0; r < 4; r++) {
                    int gr = bm + tm * 16 + quad * 4 + r;
                    if (gr < M)
                        outb[(size_t)gr * NH + cg] = (unsigned short)f2bf(acc[tm][tn][r]);
                }
            } else {
                float bv = bias[cg - NH];
                #pragma unroll
                for (int r = 0; r < 4; r++) {
                    int gr = bm + tm * 16 + quad * 4 + r;
                    if (gr < M)
                        outc[(size_t)gr * NH + (cg - NH)] = (unsigned short)f2bf(acc[tm][tn][r] + bv);
                }
            }
        }
    }
}

// ---- layer-1 agg: single fused pass, half-wave per edge ----
__global__ void agg1_kernel(const int* __restrict__ row_ptr, const int* __restrict__ ssrc,
                            const float* __restrict__ a_src, const float* __restrict__ a_dst,
                            const unsigned short* __restrict__ h1b,
                            const unsigned short* __restrict__ linb,
                            const float* __restrict__ vs2, const float* __restrict__ vd2,
                            unsigned short* __restrict__ hb,
                            float* __restrict__ a_src2, float* __restrict__ a_dst2, int Nn) {
    int node = blockIdx.x * 4 + (threadIdx.x >> 6);
    int lane = threadIdx.x & 63;
    if (node >= Nn) return;
    int beg = row_ptr[node], end = row_ptr[node + 1];
    float ad = a_dst[node];

    int half = lane >> 5, cl = lane & 31;
    float4 acc = make_float4(0.f, 0.f, 0.f, 0.f);
    float dsum = 0.f;
    const unsigned short* hcol = h1b + cl * 4;
    int j = beg + half;
    for (; j + 2 < end; j += 4) {
        int s0 = ssrc[j], s1 = ssrc[j + 2];
        float l0 = a_src[s0] + ad; l0 = (l0 > 0.f) ? l0 : NEG_SLOPE * l0;
        float l1 = a_src[s1] + ad; l1 = (l1 > 0.f) ? l1 : NEG_SLOPE * l1;
        float w0 = __expf(l0), w1 = __expf(l1);
        uint2 p0 = *(const uint2*)(hcol + (size_t)s0 * HID);
        uint2 p1 = *(const uint2*)(hcol + (size_t)s1 * HID);
        acc.x += w0 * bflo(p0.x); acc.y += w0 * bfhi(p0.x);
        acc.z += w0 * bflo(p0.y); acc.w += w0 * bfhi(p0.y);
        acc.x += w1 * bflo(p1.x); acc.y += w1 * bfhi(p1.x);
        acc.z += w1 * bflo(p1.y); acc.w += w1 * bfhi(p1.y);
        if (cl == 0) dsum += w0 + w1;
    }
    for (; j < end; j += 2) {
        int s0 = ssrc[j];
        float l = a_src[s0] + ad; l = (l > 0.f) ? l : NEG_SLOPE * l;
        float w = __expf(l);
        uint2 p = *(const uint2*)(hcol + (size_t)s0 * HID);
        acc.x += w * bflo(p.x); acc.y += w * bfhi(p.x);
        acc.z += w * bflo(p.y); acc.w += w * bfhi(p.y);
        if (cl == 0) dsum += w;
    }
    acc.x += __shfl_xor(acc.x, 32, 64);
    acc.y += __shfl_xor(acc.y, 32, 64);
    acc.z += __shfl_xor(acc.z, 32, 64);
    acc.w += __shfl_xor(acc.w, 32, 64);
    dsum = wave_reduce_sum(dsum);
    float inv = 1.f / (dsum + 1e-16f);

    int c = cl * 4;
    uint2 lb = *(const uint2*)(linb + (size_t)node * HID + c);
    float o0 = fmaxf(acc.x * inv + bflo(lb.x), 0.f);
    float o1 = fmaxf(acc.y * inv + bfhi(lb.x), 0.f);
    float o2 = fmaxf(acc.z * inv + bflo(lb.y), 0.f);
    float o3 = fmaxf(acc.w * inv + bfhi(lb.y), 0.f);
    if (half == 0) {
        uint2 pk;
        pk.x = (unsigned)(unsigned short)f2bf(o0) | ((unsigned)(unsigned short)f2bf(o1) << 16);
        pk.y = (unsigned)(unsigned short)f2bf(o2) | ((unsigned)(unsigned short)f2bf(o3) << 16);
        *(uint2*)&hb[(size_t)node * HID + c] = pk;
    }
    float ps = o0 * vs2[c] + o1 * vs2[c + 1] + o2 * vs2[c + 2] + o3 * vs2[c + 3];
    float pd = o0 * vd2[c] + o1 * vd2[c + 1] + o2 * vd2[c + 2] + o3 * vd2[c + 3];
    ps = wave_reduce_sum(ps) * 0.5f;
    pd = wave_reduce_sum(pd) * 0.5f;
    if (lane == 0) { a_src2[node] = ps; a_dst2[node] = pd; }
}

// ---- layer-2 agg: single fused pass, quarter-wave per edge; saves inv for alpha ----
__global__ void agg2_kernel(const int* __restrict__ row_ptr, const int* __restrict__ ssrc,
                            const float* __restrict__ a_src, const float* __restrict__ a_dst,
                            const unsigned short* __restrict__ h2b,
                            const unsigned short* __restrict__ lin2b,
                            float* __restrict__ out, float* __restrict__ sminv, int Nn) {
    int node = blockIdx.x * 4 + (threadIdx.x >> 6);
    int lane = threadIdx.x & 63;
    if (node >= Nn) return;
    int beg = row_ptr[node], end = row_ptr[node + 1];
    float ad = a_dst[node];

    int qh = lane >> 4, cl = lane & 15;
    float4 acc = make_float4(0.f, 0.f, 0.f, 0.f);
    float dsum = 0.f;
    const unsigned short* hcol = h2b + cl * 4;
    int j = beg + qh;
    for (; j + 4 < end; j += 8) {
        int s0 = ssrc[j], s1 = ssrc[j + 4];
        float l0 = a_src[s0] + ad; l0 = (l0 > 0.f) ? l0 : NEG_SLOPE * l0;
        float l1 = a_src[s1] + ad; l1 = (l1 > 0.f) ? l1 : NEG_SLOPE * l1;
        float w0 = __expf(l0), w1 = __expf(l1);
        uint2 p0 = *(const uint2*)(hcol + (size_t)s0 * D_OUT);
        uint2 p1 = *(const uint2*)(hcol + (size_t)s1 * D_OUT);
        acc.x += w0 * bflo(p0.x); acc.y += w0 * bfhi(p0.x);
        acc.z += w0 * bflo(p0.y); acc.w += w0 * bfhi(p0.y);
        acc.x += w1 * bflo(p1.x); acc.y += w1 * bfhi(p1.x);
        acc.z += w1 * bflo(p1.y); acc.w += w1 * bfhi(p1.y);
        if (cl == 0) dsum += w0 + w1;
    }
    for (; j < end; j += 4) {
        int s0 = ssrc[j];
        float l = a_src[s0] + ad; l = (l > 0.f) ? l : NEG_SLOPE * l;
        float w = __expf(l);
        uint2 p = *(const uint2*)(hcol + (size_t)s0 * D_OUT);
        acc.x += w * bflo(p.x); acc.y += w * bfhi(p.x);
        acc.z += w * bflo(p.y); acc.w += w * bfhi(p.y);
        if (cl == 0) dsum += w;
    }
    #pragma unroll
    for (int off = 16; off <= 32; off <<= 1) {
        acc.x += __shfl_xor(acc.x, off, 64);
        acc.y += __shfl_xor(acc.y, off, 64);
        acc.z += __shfl_xor(acc.z, off, 64);
        acc.w += __shfl_xor(acc.w, off, 64);
    }
    dsum = wave_reduce_sum(dsum);
    float inv = 1.f / (dsum + 1e-16f);
    if (lane == 0) sminv[node] = inv;

    if (qh == 0) {
        int c = cl * 4;
        uint2 lb = *(const uint2*)(lin2b + (size_t)node * D_OUT + c);
        float4 o = make_float4(acc.x * inv + bflo(lb.x), acc.y * inv + bfhi(lb.x),
                               acc.z * inv + bflo(lb.y), acc.w * inv + bfhi(lb.y));
        *(float4*)&out[(size_t)node * D_OUT + c] = o;
    }
}

// ---- alpha in original edge order ----
__global__ void alpha_kernel(const int* __restrict__ src, const int* __restrict__ dst,
                             const float* __restrict__ a_src2, const float* __restrict__ a_dst2,
                             const float* __restrict__ sminv, float* __restrict__ alpha, int E) {
    int e = blockIdx.x * 256 + threadIdx.x;
    if (e >= E) return;
    int s = src[e], d = dst[e];
    float l = a_src2[s] + a_dst2[d];
    l = (l > 0.f) ? l : NEG_SLOPE * l;
    alpha[e] = __expf(l) * sminv[d];
}

extern "C" void kernel_launch(void* const* d_in, const int* in_sizes, int n_in,
                              void* d_out, int out_size, void* d_ws, size_t ws_size,
                              hipStream_t stream) {
    const float* x        = (const float*)d_in[0];
    const int*   ei       = (const int*)d_in[1];
    const float* W_src1   = (const float*)d_in[2];
    const float* W_dst1   = (const float*)d_in[3];
    const float* att_src1 = (const float*)d_in[4];
    const float* att_dst1 = (const float*)d_in[5];
    const float* b1       = (const float*)d_in[6];
    const float* W_lin1   = (const float*)d_in[7];
    const float* b_lin1   = (const float*)d_in[8];
    const float* W_src2   = (const float*)d_in[9];
    const float* W_dst2   = (const float*)d_in[10];
    const float* att_src2 = (const float*)d_in[11];
    const float* att_dst2 = (const float*)d_in[12];
    const float* b2       = (const float*)d_in[13];
    const float* W_lin2   = (const float*)d_in[14];
    const float* b_lin2   = (const float*)d_in[15];

    const int Nn = in_sizes[0] / D_IN;   // 50000
    const int E  = in_sizes[1] / 2;      // 800000
    const int* src = ei;
    const int* dst = ei + E;

    char* w = (char*)d_ws;
    auto alloc = [&](size_t bytes) { char* p = w; w += (bytes + 255) & ~(size_t)255; return p; };
    unsigned short* xb   = (unsigned short*)alloc((size_t)Nn * D_IN * 2);   // bf16 x
    unsigned short* h1b  = (unsigned short*)alloc((size_t)Nn * HID * 2);
    unsigned short* lin1b= (unsigned short*)alloc((size_t)Nn * HID * 2);
    unsigned short* hb   = (unsigned short*)alloc((size_t)Nn * HID * 2);
    unsigned short* h2b  = (unsigned short*)alloc((size_t)Nn * D_OUT * 2);
    unsigned short* lin2b= (unsigned short*)alloc((size_t)Nn * D_OUT * 2);
    float* a_src1 = (float*)alloc((size_t)Nn * 4);
    float* a_dst1 = (float*)alloc((size_t)Nn * 4);
    float* a_src2 = (float*)alloc((size_t)Nn * 4);
    float* a_dst2 = (float*)alloc((size_t)Nn * 4);
    float* sminv  = (float*)alloc((size_t)Nn * 4);
    int*   deg    = (int*)alloc((size_t)Nn * 4);
    int*   row_ptr= (int*)alloc((size_t)(Nn + 1) * 4);
    int*   cursor = (int*)alloc((size_t)Nn * 4);
    int*   ssrc   = (int*)alloc((size_t)E * 4);
    short* Wp1    = (short*)alloc((size_t)8 * 16 * 512 * 2);  // 128 KB
    short* Wp2    = (short*)alloc((size_t)4 * 8 * 512 * 2);   // 32 KB
    float* v_src1 = (float*)alloc(D_IN * 4);
    float* v_dst1 = (float*)alloc(D_IN * 4);
    float* v_src2 = (float*)alloc(HID * 4);
    float* v_dst2 = (float*)alloc(HID * 4);
    float* bsum1  = (float*)alloc(HID * 4);
    float* bsum2  = (float*)alloc(D_OUT * 4);
    int*   bsums  = (int*)alloc(64 * 4);
    int*   boff   = (int*)alloc(64 * 4);

    float* out       = (float*)d_out;
    float* alpha_out = out + (size_t)Nn * D_OUT;

    prep_kernel<<<1, 256, 0, stream>>>(W_src1, att_src1, W_dst1, att_dst1,
                                       W_src2, att_src2, W_dst2, att_dst2,
                                       b1, b_lin1, b2, b_lin2,
                                       v_src1, v_dst1, v_src2, v_dst2, bsum1, bsum2);
    pack_kernel<<<256, 256, 0, stream>>>(W_src1, W_lin1, Wp1, 16, HID, 8 * 16 * 512);
    pack_kernel<<<64, 256, 0, stream>>>(W_src2, W_lin2, Wp2, 8, D_OUT, 4 * 8 * 512);

    hipMemsetAsync(deg, 0, (size_t)Nn * 4, stream);
    int eblocks = (E + 255) / 256;
    hist_kernel<<<eblocks, 256, 0, stream>>>(dst, E, deg);
    int nb = (Nn + 1023) / 1024;
    scan_partial<<<nb, 1024, 0, stream>>>(deg, Nn, bsums);
    scan_offsets<<<1, 64, 0, stream>>>(bsums, nb, boff);
    scan_final<<<nb, 1024, 0, stream>>>(deg, Nn, boff, row_ptr, cursor);
    scatter_kernel<<<eblocks, 256, 0, stream>>>(src, dst, E, cursor, ssrc);

    int ablocks = (Nn + 3) / 4;
    convert_kernel<<<ablocks, 256, 0, stream>>>(x, v_src1, v_dst1, xb, a_src1, a_dst1, Nn);

    int mblocks = (Nn + 63) / 64;   // 782
    gemm_direct<8, 4><<<mblocks, 256, 0, stream>>>(xb, Wp1, bsum1, h1b, lin1b, Nn);

    agg1_kernel<<<ablocks, 256, 0, stream>>>(row_ptr, ssrc, a_src1, a_dst1, h1b, lin1b,
                                             v_src2, v_dst2, hb, a_src2, a_dst2, Nn);

    gemm_direct<4, 2><<<mblocks, 256, 0, stream>>>(hb, Wp2, bsum2, h2b, lin2b, Nn);
    agg2_kernel<<<ablocks, 256, 0, stream>>>(row_ptr, ssrc, a_src2, a_dst2, h2b, lin2b,
                                             out, sminv, Nn);
    alpha_kernel<<<eblocks, 256, 0, stream>>>(src, dst, a_src2, a_dst2, sminv, alpha_out, E);
}

// Round 9
// 341.973 us; speedup vs baseline: 1.0394x; 1.0394x over previous
//
#include <hip/hip_runtime.h>
#include <math.h>

#define D_IN 256
#define HID 128
#define D_OUT 64
#define NEG_SLOPE 0.2f

typedef short short8 __attribute__((ext_vector_type(8)));
typedef float floatx4 __attribute__((ext_vector_type(4)));

__device__ __forceinline__ float wave_reduce_sum(float v) {
    #pragma unroll
    for (int off = 32; off > 0; off >>= 1) v += __shfl_xor(v, off, 64);
    return v;
}
__device__ __forceinline__ int wave_reduce_sum_i(int v) {
    #pragma unroll
    for (int off = 32; off > 0; off >>= 1) v += __shfl_xor(v, off, 64);
    return v;
}
__device__ __forceinline__ int wave_scan_incl_i(int v) {
    int lane = threadIdx.x & 63;
    #pragma unroll
    for (int off = 1; off < 64; off <<= 1) {
        int t = __shfl_up(v, off, 64);
        if (lane >= off) v += t;
    }
    return v;
}

__device__ __forceinline__ short f2bf(float f) {           // RNE f32->bf16
    unsigned u = __float_as_uint(f);
    u += 0x7fffu + ((u >> 16) & 1u);
    return (short)(u >> 16);
}
__device__ __forceinline__ unsigned pk2(float a, float b) {
    return (unsigned)(unsigned short)f2bf(a) | ((unsigned)(unsigned short)f2bf(b) << 16);
}
__device__ __forceinline__ float bflo(unsigned p) { return __uint_as_float(p << 16); }
__device__ __forceinline__ float bfhi(unsigned p) { return __uint_as_float(p & 0xffff0000u); }

// ---------- device bodies for fused dispatch ----------
__device__ void prep_body(const float* Wsrc1, const float* att_src1,
                          const float* Wdst1, const float* att_dst1,
                          const float* Wsrc2, const float* att_src2,
                          const float* Wdst2, const float* att_dst2,
                          const float* b1, const float* b_lin1,
                          const float* b2, const float* b_lin2,
                          float* v_src1, float* v_dst1, float* v_src2, float* v_dst2,
                          float* bsum1, float* bsum2) {
    int t = threadIdx.x;
    if (t < D_IN) {
        float s1 = 0.f, s2 = 0.f;
        for (int c = 0; c < HID; c++) {
            s1 += Wsrc1[t * HID + c] * att_src1[c];
            s2 += Wdst1[t * HID + c] * att_dst1[c];
        }
        v_src1[t] = s1; v_dst1[t] = s2;
    }
    if (t < HID) {
        float s1 = 0.f, s2 = 0.f;
        for (int c = 0; c < D_OUT; c++) {
            s1 += Wsrc2[t * D_OUT + c] * att_src2[c];
            s2 += Wdst2[t * D_OUT + c] * att_dst2[c];
        }
        v_src2[t] = s1; v_dst2[t] = s2;
        bsum1[t] = b1[t] + b_lin1[t];
    }
    if (t < D_OUT) bsum2[t] = b2[t] + b_lin2[t];
}

__device__ void pack_body(const float* Wa, const float* Wb, short* Wp,
                          int NTG, int NH, int total, int idx) {
    if (idx >= total) return;
    int j = idx & 7;
    int lane = (idx >> 3) & 63;
    int r = idx >> 9;
    int nt = r % NTG;
    int s = r / NTG;
    int k = s * 32 + ((lane >> 4) * 8) + j;
    int cg = nt * 16 + (lane & 15);
    const float* W = (cg < NH) ? Wa : Wb;
    int col = (cg < NH) ? cg : cg - NH;
    Wp[idx] = f2bf(W[(size_t)k * NH + col]);
}

// ---- fused: hist | pack1 | pack2 | prep (independent, block-range dispatch) ----
__global__ void fused_pre(const int* __restrict__ dst, int E, int* deg, int EB,
                          const float* W_src1, const float* W_lin1, short* Wp1,
                          const float* W_src2, const float* W_lin2, short* Wp2,
                          const float* att_src1, const float* W_dst1, const float* att_dst1,
                          const float* att_src2, const float* W_dst2, const float* att_dst2,
                          const float* b1, const float* b_lin1,
                          const float* b2, const float* b_lin2,
                          float* v_src1, float* v_dst1, float* v_src2, float* v_dst2,
                          float* bsum1, float* bsum2) {
    int bid = blockIdx.x;
    if (bid < EB) {
        int e = bid * 256 + threadIdx.x;
        if (e < E) atomicAdd(&deg[dst[e]], 1);
    } else if (bid < EB + 256) {
        pack_body(W_src1, W_lin1, Wp1, 16, HID, 8 * 16 * 512, (bid - EB) * 256 + threadIdx.x);
    } else if (bid < EB + 320) {
        pack_body(W_src2, W_lin2, Wp2, 8, D_OUT, 4 * 8 * 512, (bid - EB - 256) * 256 + threadIdx.x);
    } else {
        prep_body(W_src1, att_src1, W_dst1, att_dst1, W_src2, att_src2, W_dst2, att_dst2,
                  b1, b_lin1, b2, b_lin2, v_src1, v_dst1, v_src2, v_dst2, bsum1, bsum2);
    }
}

// ---- CSR scan ----
__global__ void scan_partial(const int* __restrict__ deg, int n, int* bsums) {
    __shared__ int ws[16];
    int i = blockIdx.x * 1024 + threadIdx.x;
    int v = (i < n) ? deg[i] : 0;
    int s = wave_reduce_sum_i(v);
    if ((threadIdx.x & 63) == 0) ws[threadIdx.x >> 6] = s;
    __syncthreads();
    if (threadIdx.x == 0) {
        int tot = 0;
        #pragma unroll
        for (int w = 0; w < 16; w++) tot += ws[w];
        bsums[blockIdx.x] = tot;
    }
}

__global__ void scan_offsets(const int* __restrict__ bsums, int nb, int* boff) {
    int lane = threadIdx.x;
    int v = (lane < nb) ? bsums[lane] : 0;
    int incl = wave_scan_incl_i(v);
    if (lane < nb) boff[lane] = incl - v;
}

__global__ void scan_final(const int* __restrict__ deg, int n, const int* __restrict__ boff,
                           int* row_ptr, int* cursor) {
    __shared__ int ws[16];
    int i = blockIdx.x * 1024 + threadIdx.x;
    int wid = threadIdx.x >> 6;
    int v = (i < n) ? deg[i] : 0;
    int sv = wave_scan_incl_i(v);
    if ((threadIdx.x & 63) == 63) ws[wid] = sv;
    __syncthreads();
    if (threadIdx.x == 0) {
        int run = 0;
        #pragma unroll
        for (int w = 0; w < 16; w++) { int t = ws[w]; ws[w] = run; run += t; }
    }
    __syncthreads();
    int excl = boff[blockIdx.x] + ws[wid] + sv - v;
    if (i < n) {
        row_ptr[i] = excl; cursor[i] = excl;
        if (i == n - 1) row_ptr[n] = excl + v;
    }
}

// ---- fused: scatter | convert (x fp32->bf16 + layer-1 att dots) ----
__global__ void fused_mid(const int* __restrict__ src, const int* __restrict__ dst, int E,
                          int* cursor, int* ssrc, int EB,
                          const float* __restrict__ X,
                          const float* __restrict__ vsrc, const float* __restrict__ vdst,
                          unsigned short* __restrict__ xb,
                          float* __restrict__ a_src, float* __restrict__ a_dst, int Nn) {
    int bid = blockIdx.x;
    if (bid < EB) {
        int e = bid * 256 + threadIdx.x;
        if (e < E) {
            int d = dst[e];
            int pos = atomicAdd(&cursor[d], 1);
            ssrc[pos] = src[e];
        }
    } else {
        int row = (bid - EB) * 4 + (threadIdx.x >> 6);
        int lane = threadIdx.x & 63;
        if (row >= Nn) return;
        float4 v = *(const float4*)(X + (size_t)row * D_IN + lane * 4);
        float4 vs = *(const float4*)(vsrc + lane * 4);
        float4 vd = *(const float4*)(vdst + lane * 4);
        float ps = v.x * vs.x + v.y * vs.y + v.z * vs.z + v.w * vs.w;
        float pd = v.x * vd.x + v.y * vd.y + v.z * vd.z + v.w * vd.w;
        ushort4 o;
        o.x = (unsigned short)f2bf(v.x); o.y = (unsigned short)f2bf(v.y);
        o.z = (unsigned short)f2bf(v.z); o.w = (unsigned short)f2bf(v.w);
        *(ushort4*)(xb + (size_t)row * D_IN + lane * 4) = o;
        ps = wave_reduce_sum(ps);
        pd = wave_reduce_sum(pd);
        if (lane == 0) { a_src[row] = ps; a_dst[row] = pd; }
    }
}

// ---- barrier-free direct-fragment MFMA GEMM (unchanged from R8) ----
template <int KS, int NT>
__global__ __launch_bounds__(256, 3) void gemm_direct(const unsigned short* __restrict__ A,
                                                      const short* __restrict__ Wp,
                                                      const float* __restrict__ bias,
                                                      unsigned short* __restrict__ outb,
                                                      unsigned short* __restrict__ outc, int M) {
    const int K = KS * 32;
    const int NTG = 4 * NT;
    const int NH = NT * 32;
    int tid = threadIdx.x;
    int wave = tid >> 6, lane = tid & 63;
    int mr = lane & 15, quad = lane >> 4;
    int bm = blockIdx.x * 64;

    floatx4 acc[4][NT];
    #pragma unroll
    for (int i = 0; i < 4; i++)
        #pragma unroll
        for (int j = 0; j < NT; j++) acc[i][j] = (floatx4){0.f, 0.f, 0.f, 0.f};

    const unsigned short* arow[4];
    #pragma unroll
    for (int tm = 0; tm < 4; tm++) {
        int gr = bm + tm * 16 + mr;
        if (gr >= M) gr = M - 1;
        arow[tm] = A + (size_t)gr * K + quad * 8;
    }
    const short* bbase = Wp + ((size_t)(wave * NT) * 64 + lane) * 8;

    #pragma unroll
    for (int s = 0; s < KS; s++) {
        short8 af[4], bf[NT];
        #pragma unroll
        for (int tm = 0; tm < 4; tm++)
            af[tm] = *(const short8*)(arow[tm] + s * 32);
        #pragma unroll
        for (int tn = 0; tn < NT; tn++)
            bf[tn] = *(const short8*)(bbase + ((size_t)s * NTG + tn) * 512);
        #pragma unroll
        for (int tn = 0; tn < NT; tn++)
            #pragma unroll
            for (int tm = 0; tm < 4; tm++)
                acc[tm][tn] = __builtin_amdgcn_mfma_f32_16x16x32_bf16(af[tm], bf[tn],
                                                                      acc[tm][tn], 0, 0, 0);
    }

    #pragma unroll
    for (int tm = 0; tm < 4; tm++) {
        #pragma unroll
        for (int tn = 0; tn < NT; tn++) {
            int cg = wave * NT * 16 + tn * 16 + mr;
            if (cg < NH) {
                #pragma unroll
                for (int r = 0; r < 4; r++) {
                    int gr = bm + tm * 16 + quad * 4 + r;
                    if (gr < M)
                        outb[(size_t)gr * NH + cg] = (unsigned short)f2bf(acc[tm][tn][r]);
                }
            } else {
                float bv = bias[cg - NH];
                #pragma unroll
                for (int r = 0; r < 4; r++) {
                    int gr = bm + tm * 16 + quad * 4 + r;
                    if (gr < M)
                        outc[(size_t)gr * NH + (cg - NH)] = (unsigned short)f2bf(acc[tm][tn][r] + bv);
                }
            }
        }
    }
}

// ---- layer-1 agg: quarter-wave per edge, uint4 (16B/lane) gathers ----
__global__ void agg1_kernel(const int* __restrict__ row_ptr, const int* __restrict__ ssrc,
                            const float* __restrict__ a_src, const float* __restrict__ a_dst,
                            const unsigned short* __restrict__ h1b,
                            const unsigned short* __restrict__ linb,
                            const float* __restrict__ vs2, const float* __restrict__ vd2,
                            unsigned short* __restrict__ hb,
                            float* __restrict__ a_src2, float* __restrict__ a_dst2, int Nn) {
    int node = blockIdx.x * 4 + (threadIdx.x >> 6);
    int lane = threadIdx.x & 63;
    if (node >= Nn) return;
    int beg = row_ptr[node], end = row_ptr[node + 1];
    float ad = a_dst[node];

    int qh = lane >> 4, cl = lane & 15;     // edge slot (4), channel group (16 x 8ch)
    float acc[8] = {0.f, 0.f, 0.f, 0.f, 0.f, 0.f, 0.f, 0.f};
    float dsum = 0.f;
    const unsigned short* hcol = h1b + cl * 8;
    int j = beg + qh;
    for (; j + 4 < end; j += 8) {
        int s0 = ssrc[j], s1 = ssrc[j + 4];
        float l0 = a_src[s0] + ad; l0 = (l0 > 0.f) ? l0 : NEG_SLOPE * l0;
        float l1 = a_src[s1] + ad; l1 = (l1 > 0.f) ? l1 : NEG_SLOPE * l1;
        float w0 = __expf(l0), w1 = __expf(l1);
        uint4 p0 = *(const uint4*)(hcol + (size_t)s0 * HID);
        uint4 p1 = *(const uint4*)(hcol + (size_t)s1 * HID);
        acc[0] += w0 * bflo(p0.x); acc[1] += w0 * bfhi(p0.x);
        acc[2] += w0 * bflo(p0.y); acc[3] += w0 * bfhi(p0.y);
        acc[4] += w0 * bflo(p0.z); acc[5] += w0 * bfhi(p0.z);
        acc[6] += w0 * bflo(p0.w); acc[7] += w0 * bfhi(p0.w);
        acc[0] += w1 * bflo(p1.x); acc[1] += w1 * bfhi(p1.x);
        acc[2] += w1 * bflo(p1.y); acc[3] += w1 * bfhi(p1.y);
        acc[4] += w1 * bflo(p1.z); acc[5] += w1 * bfhi(p1.z);
        acc[6] += w1 * bflo(p1.w); acc[7] += w1 * bfhi(p1.w);
        if (cl == 0) dsum += w0 + w1;
    }
    for (; j < end; j += 4) {
        int s0 = ssrc[j];
        float l = a_src[s0] + ad; l = (l > 0.f) ? l : NEG_SLOPE * l;
        float w = __expf(l);
        uint4 p = *(const uint4*)(hcol + (size_t)s0 * HID);
        acc[0] += w * bflo(p.x); acc[1] += w * bfhi(p.x);
        acc[2] += w * bflo(p.y); acc[3] += w * bfhi(p.y);
        acc[4] += w * bflo(p.z); acc[5] += w * bfhi(p.z);
        acc[6] += w * bflo(p.w); acc[7] += w * bfhi(p.w);
        if (cl == 0) dsum += w;
    }
    #pragma unroll
    for (int i = 0; i < 8; i++) {
        acc[i] += __shfl_xor(acc[i], 16, 64);
        acc[i] += __shfl_xor(acc[i], 32, 64);
    }
    dsum = wave_reduce_sum(dsum);
    float inv = 1.f / (dsum + 1e-16f);

    int c = cl * 8;
    uint4 lb = *(const uint4*)(linb + (size_t)node * HID + c);
    float o[8];
    o[0] = fmaxf(acc[0] * inv + bflo(lb.x), 0.f);
    o[1] = fmaxf(acc[1] * inv + bfhi(lb.x), 0.f);
    o[2] = fmaxf(acc[2] * inv + bflo(lb.y), 0.f);
    o[3] = fmaxf(acc[3] * inv + bfhi(lb.y), 0.f);
    o[4] = fmaxf(acc[4] * inv + bflo(lb.z), 0.f);
    o[5] = fmaxf(acc[5] * inv + bfhi(lb.z), 0.f);
    o[6] = fmaxf(acc[6] * inv + bflo(lb.w), 0.f);
    o[7] = fmaxf(acc[7] * inv + bfhi(lb.w), 0.f);
    if (qh == 0) {
        uint4 pk;
        pk.x = pk2(o[0], o[1]); pk.y = pk2(o[2], o[3]);
        pk.z = pk2(o[4], o[5]); pk.w = pk2(o[6], o[7]);
        *(uint4*)&hb[(size_t)node * HID + c] = pk;
    }
    float ps = 0.f, pd = 0.f;
    #pragma unroll
    for (int i = 0; i < 8; i++) { ps += o[i] * vs2[c + i]; pd += o[i] * vd2[c + i]; }
    ps = wave_reduce_sum(ps) * 0.25f;   // 4 qh groups duplicate after xor-combine
    pd = wave_reduce_sum(pd) * 0.25f;
    if (lane == 0) { a_src2[node] = ps; a_dst2[node] = pd; }
}

// ---- layer-2 agg: eighth-wave per edge, uint4 = exactly one 128B row ----
__global__ void agg2_kernel(const int* __restrict__ row_ptr, const int* __restrict__ ssrc,
                            const float* __restrict__ a_src, const float* __restrict__ a_dst,
                            const unsigned short* __restrict__ h2b,
                            const unsigned short* __restrict__ lin2b,
                            float* __restrict__ out, float* __restrict__ sminv, int Nn) {
    int node = blockIdx.x * 4 + (threadIdx.x >> 6);
    int lane = threadIdx.x & 63;
    if (node >= Nn) return;
    int beg = row_ptr[node], end = row_ptr[node + 1];
    float ad = a_dst[node];

    int oh = lane >> 3, cl = lane & 7;      // edge slot (8), channel group (8 x 8ch)
    float acc[8] = {0.f, 0.f, 0.f, 0.f, 0.f, 0.f, 0.f, 0.f};
    float dsum = 0.f;
    const unsigned short* hcol = h2b + cl * 8;
    int j = beg + oh;
    for (; j + 8 < end; j += 16) {
        int s0 = ssrc[j], s1 = ssrc[j + 8];
        float l0 = a_src[s0] + ad; l0 = (l0 > 0.f) ? l0 : NEG_SLOPE * l0;
        float l1 = a_src[s1] + ad; l1 = (l1 > 0.f) ? l1 : NEG_SLOPE * l1;
        float w0 = __expf(l0), w1 = __expf(l1);
        uint4 p0 = *(const uint4*)(hcol + (size_t)s0 * D_OUT);
        uint4 p1 = *(const uint4*)(hcol + (size_t)s1 * D_OUT);
        acc[0] += w0 * bflo(p0.x); acc[1] += w0 * bfhi(p0.x);
        acc[2] += w0 * bflo(p0.y); acc[3] += w0 * bfhi(p0.y);
        acc[4] += w0 * bflo(p0.z); acc[5] += w0 * bfhi(p0.z);
        acc[6] += w0 * bflo(p0.w); acc[7] += w0 * bfhi(p0.w);
        acc[0] += w1 * bflo(p1.x); acc[1] += w1 * bfhi(p1.x);
        acc[2] += w1 * bflo(p1.y); acc[3] += w1 * bfhi(p1.y);
        acc[4] += w1 * bflo(p1.z); acc[5] += w1 * bfhi(p1.z);
        acc[6] += w1 * bflo(p1.w); acc[7] += w1 * bfhi(p1.w);
        if (cl == 0) dsum += w0 + w1;
    }
    for (; j < end; j += 8) {
        int s0 = ssrc[j];
        float l = a_src[s0] + ad; l = (l > 0.f) ? l : NEG_SLOPE * l;
        float w = __expf(l);
        uint4 p = *(const uint4*)(hcol + (size_t)s0 * D_OUT);
        acc[0] += w * bflo(p.x); acc[1] += w * bfhi(p.x);
        acc[2] += w * bflo(p.y); acc[3] += w * bfhi(p.y);
        acc[4] += w * bflo(p.z); acc[5] += w * bfhi(p.z);
        acc[6] += w * bflo(p.w); acc[7] += w * bfhi(p.w);
        if (cl == 0) dsum += w;
    }
    #pragma unroll
    for (int i = 0; i < 8; i++) {
        acc[i] += __shfl_xor(acc[i], 8, 64);
        acc[i] += __shfl_xor(acc[i], 16, 64);
        acc[i] += __shfl_xor(acc[i], 32, 64);
    }
    dsum = wave_reduce_sum(dsum);
    float inv = 1.f / (dsum + 1e-16f);
    if (lane == 0) sminv[node] = inv;

    if (oh == 0) {
        int c = cl * 8;
        uint4 lb = *(const uint4*)(lin2b + (size_t)node * D_OUT + c);
        float4 oa = make_float4(acc[0] * inv + bflo(lb.x), acc[1] * inv + bfhi(lb.x),
                                acc[2] * inv + bflo(lb.y), acc[3] * inv + bfhi(lb.y));
        float4 ob = make_float4(acc[4] * inv + bflo(lb.z), acc[5] * inv + bfhi(lb.z),
                                acc[6] * inv + bflo(lb.w), acc[7] * inv + bfhi(lb.w));
        *(float4*)&out[(size_t)node * D_OUT + c] = oa;
        *(float4*)&out[(size_t)node * D_OUT + c + 4] = ob;
    }
}

// ---- alpha in original edge order ----
__global__ void alpha_kernel(const int* __restrict__ src, const int* __restrict__ dst,
                             const float* __restrict__ a_src2, const float* __restrict__ a_dst2,
                             const float* __restrict__ sminv, float* __restrict__ alpha, int E) {
    int e = blockIdx.x * 256 + threadIdx.x;
    if (e >= E) return;
    int s = src[e], d = dst[e];
    float l = a_src2[s] + a_dst2[d];
    l = (l > 0.f) ? l : NEG_SLOPE * l;
    alpha[e] = __expf(l) * sminv[d];
}

extern "C" void kernel_launch(void* const* d_in, const int* in_sizes, int n_in,
                              void* d_out, int out_size, void* d_ws, size_t ws_size,
                              hipStream_t stream) {
    const float* x        = (const float*)d_in[0];
    const int*   ei       = (const int*)d_in[1];
    const float* W_src1   = (const float*)d_in[2];
    const float* W_dst1   = (const float*)d_in[3];
    const float* att_src1 = (const float*)d_in[4];
    const float* att_dst1 = (const float*)d_in[5];
    const float* b1       = (const float*)d_in[6];
    const float* W_lin1   = (const float*)d_in[7];
    const float* b_lin1   = (const float*)d_in[8];
    const float* W_src2   = (const float*)d_in[9];
    const float* W_dst2   = (const float*)d_in[10];
    const float* att_src2 = (const float*)d_in[11];
    const float* att_dst2 = (const float*)d_in[12];
    const float* b2       = (const float*)d_in[13];
    const float* W_lin2   = (const float*)d_in[14];
    const float* b_lin2   = (const float*)d_in[15];

    const int Nn = in_sizes[0] / D_IN;   // 50000
    const int E  = in_sizes[1] / 2;      // 800000
    const int* src = ei;
    const int* dst = ei + E;

    char* w = (char*)d_ws;
    auto alloc = [&](size_t bytes) { char* p = w; w += (bytes + 255) & ~(size_t)255; return p; };
    unsigned short* xb   = (unsigned short*)alloc((size_t)Nn * D_IN * 2);
    unsigned short* h1b  = (unsigned short*)alloc((size_t)Nn * HID * 2);
    unsigned short* lin1b= (unsigned short*)alloc((size_t)Nn * HID * 2);
    unsigned short* hb   = (unsigned short*)alloc((size_t)Nn * HID * 2);
    unsigned short* h2b  = (unsigned short*)alloc((size_t)Nn * D_OUT * 2);
    unsigned short* lin2b= (unsigned short*)alloc((size_t)Nn * D_OUT * 2);
    float* a_src1 = (float*)alloc((size_t)Nn * 4);
    float* a_dst1 = (float*)alloc((size_t)Nn * 4);
    float* a_src2 = (float*)alloc((size_t)Nn * 4);
    float* a_dst2 = (float*)alloc((size_t)Nn * 4);
    float* sminv  = (float*)alloc((size_t)Nn * 4);
    int*   deg    = (int*)alloc((size_t)Nn * 4);
    int*   row_ptr= (int*)alloc((size_t)(Nn + 1) * 4);
    int*   cursor = (int*)alloc((size_t)Nn * 4);
    int*   ssrc   = (int*)alloc((size_t)E * 4);
    short* Wp1    = (short*)alloc((size_t)8 * 16 * 512 * 2);  // 128 KB
    short* Wp2    = (short*)alloc((size_t)4 * 8 * 512 * 2);   // 32 KB
    float* v_src1 = (float*)alloc(D_IN * 4);
    float* v_dst1 = (float*)alloc(D_IN * 4);
    float* v_src2 = (float*)alloc(HID * 4);
    float* v_dst2 = (float*)alloc(HID * 4);
    float* bsum1  = (float*)alloc(HID * 4);
    float* bsum2  = (float*)alloc(D_OUT * 4);
    int*   bsums  = (int*)alloc(64 * 4);
    int*   boff   = (int*)alloc(64 * 4);

    float* out       = (float*)d_out;
    float* alpha_out = out + (size_t)Nn * D_OUT;

    hipMemsetAsync(deg, 0, (size_t)Nn * 4, stream);

    int eblocks = (E + 255) / 256;       // 3125
    fused_pre<<<eblocks + 321, 256, 0, stream>>>(dst, E, deg, eblocks,
                                                 W_src1, W_lin1, Wp1, W_src2, W_lin2, Wp2,
                                                 att_src1, W_dst1, att_dst1,
                                                 att_src2, W_dst2, att_dst2,
                                                 b1, b_lin1, b2, b_lin2,
                                                 v_src1, v_dst1, v_src2, v_dst2, bsum1, bsum2);

    int nb = (Nn + 1023) / 1024;
    scan_partial<<<nb, 1024, 0, stream>>>(deg, Nn, bsums);
    scan_offsets<<<1, 64, 0, stream>>>(bsums, nb, boff);
    scan_final<<<nb, 1024, 0, stream>>>(deg, Nn, boff, row_ptr, cursor);

    int ablocks = (Nn + 3) / 4;          // 12500
    fused_mid<<<eblocks + ablocks, 256, 0, stream>>>(src, dst, E, cursor, ssrc, eblocks,
                                                     x, v_src1, v_dst1, xb, a_src1, a_dst1, Nn);

    int mblocks = (Nn + 63) / 64;        // 782
    gemm_direct<8, 4><<<mblocks, 256, 0, stream>>>(xb, Wp1, bsum1, h1b, lin1b, Nn);

    agg1_kernel<<<ablocks, 256, 0, stream>>>(row_ptr, ssrc, a_src1, a_dst1, h1b, lin1b,
                                             v_src2, v_dst2, hb, a_src2, a_dst2, Nn);

    gemm_direct<4, 2><<<mblocks, 256, 0, stream>>>(hb, Wp2, bsum2, h2b, lin2b, Nn);
    agg2_kernel<<<ablocks, 256, 0, stream>>>(row_ptr, ssrc, a_src2, a_dst2, h2b, lin2b,
                                             out, sminv, Nn);
    alpha_kernel<<<eblocks, 256, 0, stream>>>(src, dst, a_src2, a_dst2, sminv, alpha_out, E);
}